// Round 17
// baseline (247.609 us; speedup 1.0000x reference)
//
#include <hip/hip_runtime.h>
#include <hip/hip_bf16.h>

#define NN 20000
#define NE 320000
#define NCH 17        // 16 conv slots + 1 fc slot, K chunks of 32
#define SROWU 552     // per-node LDS row stride (ushorts): 544 + 8 pad
#define CAP 64        // per-node edge bucket capacity (mean deg 16)
#define W2U (2 * NCH * 512)   // per-layer W2frag ushorts = 17408

typedef __attribute__((ext_vector_type(8))) short short8;
typedef __attribute__((ext_vector_type(4))) float f32x4;

__device__ __forceinline__ unsigned short f2bf(float v) {
    unsigned u = __float_as_uint(v);
    unsigned r = (u + 0x7fffu + ((u >> 16) & 1u)) >> 16;
    return (unsigned short)r;
}
__device__ __forceinline__ float bf2f(unsigned short s) {
    return __uint_as_float(((unsigned)s) << 16);
}

struct WPtrs { const float* cw[4]; const float* fw[4]; };

// x layout: per node 16 dwords; dword f = bf16(x[f]) | bf16(x[f+16])<<16

// ---- one build dispatch:
// [0,1250): edge->bucket fill (+basis weights);  [1250,1329): feat cast;
// [1329,1363): W2frag (pre-swizzled MFMA B-fragments, all 4 layers)
__global__ __launch_bounds__(256) void buildfill_kernel(const int* __restrict__ ei,
                                                        const int* __restrict__ ej,
                                                        const float* __restrict__ attr,
                                                        int* __restrict__ cnt,
                                                        uint4* __restrict__ bucket,
                                                        WPtrs wp,
                                                        const float* __restrict__ feat,
                                                        unsigned* __restrict__ x0,
                                                        unsigned short* __restrict__ w2frag) {
    int b = blockIdx.x, t = threadIdx.x;
    if (b < 1250) {
        int e = b * 256 + t;                     // 1250*256 == NE exactly
        int i = ei[e], j = ej[e];
        float2 a = ((const float2*)attr)[e];
        float d0 = fminf(fmaxf(a.x, -1.f), 1.f);
        float d1 = fminf(fmaxf(a.y, -1.f), 1.f);
        float tx = (d0 + 1.f) * 1.5f;
        float ty = (d1 + 1.f) * 1.5f;
        int ix = min(2, max(0, (int)floorf(tx)));
        int iy = min(2, max(0, (int)floorf(ty)));
        float ux = tx - (float)ix;
        float uy = ty - (float)iy;
        float m = (i != j) ? 1.f : 0.f;   // centerIgnore
        uint4 mm;
        mm.x = (unsigned)j | ((unsigned)(ix * 4 + iy) << 16);
        mm.y = (unsigned)f2bf((1.f - ux) * (1.f - uy) * m)
             | ((unsigned)f2bf((1.f - ux) * uy * m) << 16);
        mm.z = (unsigned)f2bf(ux * (1.f - uy) * m)
             | ((unsigned)f2bf(ux * uy * m) << 16);
        mm.w = 0;
        int slot = atomicAdd(&cnt[i], 1);
        if (slot < CAP) bucket[(size_t)i * CAP + slot] = mm;
    } else if (b < 1329) {
        int n = (b - 1250) * 256 + t;            // 79*256 = 20224 >= 20000
        if (n < NN) {
            const float4* fr = (const float4*)(feat + (size_t)n * 32);
            float4 v0 = fr[0], v1 = fr[1], v2 = fr[2], v3 = fr[3];
            float4 v4 = fr[4], v5 = fr[5], v6 = fr[6], v7 = fr[7];
            float lo[16] = {v0.x, v0.y, v0.z, v0.w, v1.x, v1.y, v1.z, v1.w,
                            v2.x, v2.y, v2.z, v2.w, v3.x, v3.y, v3.z, v3.w};
            float hi[16] = {v4.x, v4.y, v4.z, v4.w, v5.x, v5.y, v5.z, v5.w,
                            v6.x, v6.y, v6.z, v6.w, v7.x, v7.y, v7.z, v7.w};
            unsigned o[16];
#pragma unroll
            for (int f = 0; f < 16; f++)
                o[f] = (unsigned)f2bf(lo[f]) | ((unsigned)f2bf(hi[f]) << 16);
            uint4* dst = (uint4*)(x0 + (size_t)n * 16);
#pragma unroll
            for (int q = 0; q < 4; q++) {
                uint4 w; w.x = o[q*4]; w.y = o[q*4+1]; w.z = o[q*4+2]; w.w = o[q*4+3];
                dst[q] = w;
            }
        }
    } else {
        int id2 = (b - 1329) * 256 + t;          // 4l * 2tile * 17c * 64lane = 8704
        if (id2 < 8704) {
            int lane = id2 & 63;
            int c = (id2 >> 6) % NCH;
            int lt = id2 / (NCH * 64);
            int l = lt >> 1, tt = lt & 1;
            int kb = (lane >> 4) * 8;
            int col = tt * 16 + (lane & 15);
            short8 o;
#pragma unroll
            for (int i = 0; i < 8; i++) {
                int k = c * 32 + kb + i;
                float v = (k < 512) ? wp.cw[l][(size_t)k * 32 + col]
                                    : wp.fw[l][(size_t)(k - 512) * 32 + col];
                o[i] = (short)f2bf(v);
            }
            *(short8*)(w2frag + (size_t)id2 * 8) = o;
        }
    }
}

// ---- fused layer: 16 nodes/block, 1 wave/node.
// Phase A (scatter-by-MFMA): S_i = Phi_i^T . X_i, one mfma_16x16x32 per
// B-fragment per 32-edge chunk; fully-clamped octet groups skip their loads.
// D packed to bf16 in LDS.
// Phase B: waves 0,1: ans = S . W2 (17 MFMA); bias+residual issued at entry.
__global__ __launch_bounds__(1024, 8) void fused_kernel(const unsigned* __restrict__ xin,
                                                        unsigned short* __restrict__ xout,
                                                        const uint4* __restrict__ bucket,
                                                        const int* __restrict__ cnt,
                                                        const unsigned short* __restrict__ w2frag,
                                                        const float* __restrict__ bias,
                                                        float* __restrict__ ansbuf,
                                                        float* __restrict__ outf,
                                                        int mode) {
    __shared__ unsigned short su[16][SROWU];
    int tid = threadIdx.x;
    int wv = tid >> 6, lane = tid & 63;
    int fcol = lane & 15;              // A-row (slot) / B-col (feature) role
    int kg = lane >> 4;                // edge octet within chunk
    int node = blockIdx.x * 16 + wv;
    int deg = min(cnt[node], CAP);
    const uint4* em = bucket + (size_t)node * CAP;

    // ---- issue-early epilogue loads (latency hides under phase A)
    float bsv = 0.f;
    float resv[4] = {0.f, 0.f, 0.f, 0.f};
    if (wv < 2) {
        int fo = wv * 16 + (lane & 15);
        bsv = bias[fo];
        if (mode) {
#pragma unroll
            for (int r = 0; r < 4; r++)
                resv[r] = ansbuf[(size_t)(blockIdx.x * 16 + (lane >> 4) * 4 + r) * 32 + fo];
        }
    }

    f32x4 acc0 = {0.f, 0.f, 0.f, 0.f};
    f32x4 acc1 = {0.f, 0.f, 0.f, 0.f};

    for (int qb = 0; qb < deg; qb += 32) {
        int qa = qb + kg * 8;
        uint4 mm[8];
        unsigned xv[8];
        if (qa < deg) {                // whole octet live? else skip loads
            int last = deg - 1;
#pragma unroll
            for (int i = 0; i < 8; i++) mm[i] = em[min(qa + i, last)];
#pragma unroll
            for (int i = 0; i < 8; i++)
                xv[i] = xin[(size_t)(mm[i].x & 0xFFFF) * 16 + fcol];
        } else {
#pragma unroll
            for (int i = 0; i < 8; i++) {
                mm[i].x = 0; mm[i].y = 0; mm[i].z = 0; mm[i].w = 0; xv[i] = 0;
            }
        }
        short8 av, bv0, bv1;
#pragma unroll
        for (int i = 0; i < 8; i++) {
            bv0[i] = (short)(unsigned short)(xv[i] & 0xFFFF);
            bv1[i] = (short)(unsigned short)(xv[i] >> 16);
            int d = fcol - (int)(mm[i].x >> 16);
            unsigned sel = (d & 4) ? mm[i].z : mm[i].y;
            unsigned bits = (d & 1) ? (sel >> 16) : (sel & 0xFFFFu);
            if ((d & ~5) || (qa + i >= deg)) bits = 0u;
            av[i] = (short)bits;
        }
        acc0 = __builtin_amdgcn_mfma_f32_16x16x32_bf16(av, bv0, acc0, 0, 0, 0);
        acc1 = __builtin_amdgcn_mfma_f32_16x16x32_bf16(av, bv1, acc1, 0, 0, 0);
    }
    // D -> LDS as bf16: lane holds D[slot = kg*4+r][fin = fcol and fcol+16]
#pragma unroll
    for (int r = 0; r < 4; r++) {
        int sr = kg * 4 + r;
        su[wv][sr * 32 + fcol]      = f2bf(acc0[r]);
        su[wv][sr * 32 + 16 + fcol] = f2bf(acc1[r]);
    }
    if (lane < 32) {   // fc slot: own features (bf16 bits direct from x)
        unsigned xv = xin[(size_t)node * 16 + (lane & 15)];
        su[wv][512 + lane] = (unsigned short)((lane < 16) ? (xv & 0xFFFF) : (xv >> 16));
    }
    __syncthreads();

    if (wv < 2) {
        int row = lane & 15;            // A-row = node within block
        int kb = (lane >> 4) * 8;
        const unsigned short* bp = w2frag + (size_t)wv * NCH * 512 + lane * 8;
        f32x4 acc = {0.f, 0.f, 0.f, 0.f};
#pragma unroll
        for (int c = 0; c < NCH; c++) {
            short8 av = *(const short8*)&su[row][c * 32 + kb];
            short8 bv = *(const short8*)(bp + (size_t)c * 512);
            acc = __builtin_amdgcn_mfma_f32_16x16x32_bf16(av, bv, acc, 0, 0, 0);
        }
        // D: col=lane&15 (feature), row=(lane>>4)*4+r (node within block)
        int fo = wv * 16 + (lane & 15);
        // interleaved xout position (ushort index within node): (fo&15)*2 + (fo>>4)
        int xpos = (fo & 15) * 2 + (fo >> 4);
#pragma unroll
        for (int r = 0; r < 4; r++) {
            int nd = blockIdx.x * 16 + (lane >> 4) * 4 + r;
            float val = acc[r] + bsv + resv[r];
            if (mode == 2) {
                outf[(size_t)nd * 32 + fo] = val * (1.f / 128.f);
            } else {
                ansbuf[(size_t)nd * 32 + fo] = val;
                xout[(size_t)nd * 32 + xpos] = f2bf(fmaxf(val, 0.f));
            }
        }
    }
}

extern "C" void kernel_launch(void* const* d_in, const int* in_sizes, int n_in,
                              void* d_out, int out_size, void* d_ws, size_t ws_size,
                              hipStream_t stream) {
    const float* feat = (const float*)d_in[0];
    const int* ei = (const int*)d_in[1];
    const int* ej = (const int*)d_in[2];
    const float* attr = (const float*)d_in[3];
    WPtrs wp;
    const float* fcB[4];
    if (n_in >= 16) {
        for (int l = 0; l < 4; l++) {
            wp.cw[l] = (const float*)d_in[4 + l];
            wp.fw[l] = (const float*)d_in[8 + l];
            fcB[l]   = (const float*)d_in[12 + l];
        }
    } else {
        const float* cb = (const float*)d_in[4];
        const float* fb = (const float*)d_in[5];
        const float* bb = (const float*)d_in[6];
        for (int l = 0; l < 4; l++) {
            wp.cw[l] = cb + (size_t)l * 16 * 32 * 32;
            wp.fw[l] = fb + (size_t)l * 32 * 32;
            fcB[l]   = bb + (size_t)l * 32;
        }
    }

    char* p = (char*)d_ws;
    auto alloc = [&](size_t bytes) -> void* {
        void* r = (void*)p;
        p += (bytes + 255) & ~(size_t)255;
        return r;
    };
    unsigned short* w2frag = (unsigned short*)alloc((size_t)4 * W2U * sizeof(unsigned short));
    uint4* bucket = (uint4*)alloc((size_t)NN * CAP * sizeof(uint4));
    int* cnt      = (int*)alloc((size_t)NN * sizeof(int));
    unsigned* xA  = (unsigned*)alloc((size_t)NN * 16 * sizeof(unsigned));
    unsigned* xB  = (unsigned*)alloc((size_t)NN * 16 * sizeof(unsigned));
    float* ans    = (float*)alloc((size_t)NN * 32 * sizeof(float));
    float* outf   = (float*)d_out;

    hipMemsetAsync(cnt, 0, (size_t)NN * sizeof(int), stream);

    buildfill_kernel<<<1363, 256, 0, stream>>>(ei, ej, attr, cnt, bucket,
                                               wp, feat, xA, w2frag);

    fused_kernel<<<NN / 16, 1024, 0, stream>>>(xA, (unsigned short*)xB, bucket, cnt,
                                               w2frag + 0 * (size_t)W2U, fcB[0], ans, outf, 0);
    fused_kernel<<<NN / 16, 1024, 0, stream>>>(xB, (unsigned short*)xA, bucket, cnt,
                                               w2frag + 1 * (size_t)W2U, fcB[1], ans, outf, 1);
    fused_kernel<<<NN / 16, 1024, 0, stream>>>(xA, (unsigned short*)xB, bucket, cnt,
                                               w2frag + 2 * (size_t)W2U, fcB[2], ans, outf, 1);
    fused_kernel<<<NN / 16, 1024, 0, stream>>>(xB, (unsigned short*)xA, bucket, cnt,
                                               w2frag + 3 * (size_t)W2U, fcB[3], ans, outf, 2);
}

// Round 18
// 222.369 us; speedup vs baseline: 1.1135x; 1.1135x over previous
//
#include <hip/hip_runtime.h>
#include <hip/hip_bf16.h>

#define NN 20000
#define NE 320000
#define NCH 17        // 16 conv slots + 1 fc slot, K chunks of 32
#define SROWU 552     // per-node LDS row stride (ushorts): 544 + 8 pad
#define CAP 64        // per-node edge bucket capacity (mean deg 16)
#define W2U (2 * NCH * 512)   // per-layer W2frag ushorts = 17408

typedef __attribute__((ext_vector_type(8))) short short8;
typedef __attribute__((ext_vector_type(4))) float f32x4;

__device__ __forceinline__ unsigned short f2bf(float v) {
    unsigned u = __float_as_uint(v);
    unsigned r = (u + 0x7fffu + ((u >> 16) & 1u)) >> 16;
    return (unsigned short)r;
}
__device__ __forceinline__ float bf2f(unsigned short s) {
    return __uint_as_float(((unsigned)s) << 16);
}

struct WPtrs { const float* cw[4]; const float* fw[4]; };

// x layout: per node 16 dwords; dword f = bf16(x[f]) | bf16(x[f+16])<<16

// ---- one build dispatch:
// [0,1250): edge->bucket fill (+basis weights);  [1250,1329): feat cast;
// [1329,1363): W2frag (pre-swizzled MFMA B-fragments, all 4 layers)
__global__ __launch_bounds__(256) void buildfill_kernel(const int* __restrict__ ei,
                                                        const int* __restrict__ ej,
                                                        const float* __restrict__ attr,
                                                        int* __restrict__ cnt,
                                                        uint4* __restrict__ bucket,
                                                        WPtrs wp,
                                                        const float* __restrict__ feat,
                                                        unsigned* __restrict__ x0,
                                                        unsigned short* __restrict__ w2frag) {
    int b = blockIdx.x, t = threadIdx.x;
    if (b < 1250) {
        int e = b * 256 + t;                     // 1250*256 == NE exactly
        int i = ei[e], j = ej[e];
        float2 a = ((const float2*)attr)[e];
        float d0 = fminf(fmaxf(a.x, -1.f), 1.f);
        float d1 = fminf(fmaxf(a.y, -1.f), 1.f);
        float tx = (d0 + 1.f) * 1.5f;
        float ty = (d1 + 1.f) * 1.5f;
        int ix = min(2, max(0, (int)floorf(tx)));
        int iy = min(2, max(0, (int)floorf(ty)));
        float ux = tx - (float)ix;
        float uy = ty - (float)iy;
        float m = (i != j) ? 1.f : 0.f;   // centerIgnore
        uint4 mm;
        mm.x = (unsigned)j | ((unsigned)(ix * 4 + iy) << 16);
        mm.y = (unsigned)f2bf((1.f - ux) * (1.f - uy) * m)
             | ((unsigned)f2bf((1.f - ux) * uy * m) << 16);
        mm.z = (unsigned)f2bf(ux * (1.f - uy) * m)
             | ((unsigned)f2bf(ux * uy * m) << 16);
        mm.w = 0;
        int slot = atomicAdd(&cnt[i], 1);
        if (slot < CAP) bucket[(size_t)i * CAP + slot] = mm;
    } else if (b < 1329) {
        int n = (b - 1250) * 256 + t;            // 79*256 = 20224 >= 20000
        if (n < NN) {
            const float4* fr = (const float4*)(feat + (size_t)n * 32);
            float4 v0 = fr[0], v1 = fr[1], v2 = fr[2], v3 = fr[3];
            float4 v4 = fr[4], v5 = fr[5], v6 = fr[6], v7 = fr[7];
            float lo[16] = {v0.x, v0.y, v0.z, v0.w, v1.x, v1.y, v1.z, v1.w,
                            v2.x, v2.y, v2.z, v2.w, v3.x, v3.y, v3.z, v3.w};
            float hi[16] = {v4.x, v4.y, v4.z, v4.w, v5.x, v5.y, v5.z, v5.w,
                            v6.x, v6.y, v6.z, v6.w, v7.x, v7.y, v7.z, v7.w};
            unsigned o[16];
#pragma unroll
            for (int f = 0; f < 16; f++)
                o[f] = (unsigned)f2bf(lo[f]) | ((unsigned)f2bf(hi[f]) << 16);
            uint4* dst = (uint4*)(x0 + (size_t)n * 16);
#pragma unroll
            for (int q = 0; q < 4; q++) {
                uint4 w; w.x = o[q*4]; w.y = o[q*4+1]; w.z = o[q*4+2]; w.w = o[q*4+3];
                dst[q] = w;
            }
        }
    } else {
        int id2 = (b - 1329) * 256 + t;          // 4l * 2tile * 17c * 64lane = 8704
        if (id2 < 8704) {
            int lane = id2 & 63;
            int c = (id2 >> 6) % NCH;
            int lt = id2 / (NCH * 64);
            int l = lt >> 1, tt = lt & 1;
            int kb = (lane >> 4) * 8;
            int col = tt * 16 + (lane & 15);
            short8 o;
#pragma unroll
            for (int i = 0; i < 8; i++) {
                int k = c * 32 + kb + i;
                float v = (k < 512) ? wp.cw[l][(size_t)k * 32 + col]
                                    : wp.fw[l][(size_t)(k - 512) * 32 + col];
                o[i] = (short)f2bf(v);
            }
            *(short8*)(w2frag + (size_t)id2 * 8) = o;
        }
    }
}

// ---- fused layer: 16 nodes/block, 1 wave/node.  (R14 structure)
// Phase A (scatter-by-MFMA): S_i = Phi_i^T . X_i, one mfma_16x16x32 per
// B-fragment per 32-edge chunk; D packed to bf16 in LDS.
// Phase B: waves 0,1: ans = S . W2 -- per chunk ONE ds_read_b128 for A,
// one for W, one MFMA. +bias/residual/relu.
__global__ __launch_bounds__(1024, 8) void fused_kernel(const unsigned* __restrict__ xin,
                                                        unsigned short* __restrict__ xout,
                                                        const uint4* __restrict__ bucket,
                                                        const int* __restrict__ cnt,
                                                        const unsigned short* __restrict__ w2frag,
                                                        const float* __restrict__ bias,
                                                        float* __restrict__ ansbuf,
                                                        float* __restrict__ outf,
                                                        int mode) {
    __shared__ unsigned short su[16][SROWU];
    int tid = threadIdx.x;
    int wv = tid >> 6, lane = tid & 63;
    int fcol = lane & 15;              // A-row (slot) / B-col (feature) role
    int kg = lane >> 4;                // edge octet within chunk
    int node = blockIdx.x * 16 + wv;
    int deg = min(cnt[node], CAP);
    const uint4* em = bucket + (size_t)node * CAP;

    f32x4 acc0 = {0.f, 0.f, 0.f, 0.f};
    f32x4 acc1 = {0.f, 0.f, 0.f, 0.f};

    for (int qb = 0; qb < deg; qb += 32) {
        int last = deg - 1;
        int qa = qb + kg * 8;
        uint4 mm[8];
#pragma unroll
        for (int i = 0; i < 8; i++) mm[i] = em[min(qa + i, last)];
        unsigned xv[8];
#pragma unroll
        for (int i = 0; i < 8; i++)
            xv[i] = xin[(size_t)(mm[i].x & 0xFFFF) * 16 + fcol];
        short8 av, bv0, bv1;
#pragma unroll
        for (int i = 0; i < 8; i++) {
            bv0[i] = (short)(unsigned short)(xv[i] & 0xFFFF);
            bv1[i] = (short)(unsigned short)(xv[i] >> 16);
            int d = fcol - (int)(mm[i].x >> 16);
            unsigned sel = (d & 4) ? mm[i].z : mm[i].y;
            unsigned bits = (d & 1) ? (sel >> 16) : (sel & 0xFFFFu);
            if ((d & ~5) || (qa + i >= deg)) bits = 0u;
            av[i] = (short)bits;
        }
        acc0 = __builtin_amdgcn_mfma_f32_16x16x32_bf16(av, bv0, acc0, 0, 0, 0);
        acc1 = __builtin_amdgcn_mfma_f32_16x16x32_bf16(av, bv1, acc1, 0, 0, 0);
    }
    // D -> LDS as bf16: lane holds D[slot = kg*4+r][fin = fcol and fcol+16]
#pragma unroll
    for (int r = 0; r < 4; r++) {
        int sr = kg * 4 + r;
        su[wv][sr * 32 + fcol]      = f2bf(acc0[r]);
        su[wv][sr * 32 + 16 + fcol] = f2bf(acc1[r]);
    }
    if (lane < 32) {   // fc slot: own features (bf16 bits direct from x)
        unsigned xv = xin[(size_t)node * 16 + (lane & 15)];
        su[wv][512 + lane] = (unsigned short)((lane < 16) ? (xv & 0xFFFF) : (xv >> 16));
    }
    __syncthreads();

    if (wv < 2) {
        int row = lane & 15;            // A-row = node within block
        int kb = (lane >> 4) * 8;
        const unsigned short* bp = w2frag + (size_t)wv * NCH * 512 + lane * 8;
        f32x4 acc = {0.f, 0.f, 0.f, 0.f};
#pragma unroll
        for (int c = 0; c < NCH; c++) {
            short8 av = *(const short8*)&su[row][c * 32 + kb];
            short8 bv = *(const short8*)(bp + (size_t)c * 512);
            acc = __builtin_amdgcn_mfma_f32_16x16x32_bf16(av, bv, acc, 0, 0, 0);
        }
        // D: col=lane&15 (feature), row=(lane>>4)*4+r (node within block)
        int fo = wv * 16 + (lane & 15);
        float bs = bias[fo];
        // interleaved xout position (ushort index within node): (fo&15)*2 + (fo>>4)
        int xpos = (fo & 15) * 2 + (fo >> 4);
#pragma unroll
        for (int r = 0; r < 4; r++) {
            int nd = blockIdx.x * 16 + (lane >> 4) * 4 + r;
            float val = acc[r] + bs;
            if (mode) val += ansbuf[(size_t)nd * 32 + fo];
            if (mode == 2) {
                outf[(size_t)nd * 32 + fo] = val * (1.f / 128.f);
            } else {
                ansbuf[(size_t)nd * 32 + fo] = val;
                xout[(size_t)nd * 32 + xpos] = f2bf(fmaxf(val, 0.f));
            }
        }
    }
}

extern "C" void kernel_launch(void* const* d_in, const int* in_sizes, int n_in,
                              void* d_out, int out_size, void* d_ws, size_t ws_size,
                              hipStream_t stream) {
    const float* feat = (const float*)d_in[0];
    const int* ei = (const int*)d_in[1];
    const int* ej = (const int*)d_in[2];
    const float* attr = (const float*)d_in[3];
    WPtrs wp;
    const float* fcB[4];
    if (n_in >= 16) {
        for (int l = 0; l < 4; l++) {
            wp.cw[l] = (const float*)d_in[4 + l];
            wp.fw[l] = (const float*)d_in[8 + l];
            fcB[l]   = (const float*)d_in[12 + l];
        }
    } else {
        const float* cb = (const float*)d_in[4];
        const float* fb = (const float*)d_in[5];
        const float* bb = (const float*)d_in[6];
        for (int l = 0; l < 4; l++) {
            wp.cw[l] = cb + (size_t)l * 16 * 32 * 32;
            wp.fw[l] = fb + (size_t)l * 32 * 32;
            fcB[l]   = bb + (size_t)l * 32;
        }
    }

    char* p = (char*)d_ws;
    auto alloc = [&](size_t bytes) -> void* {
        void* r = (void*)p;
        p += (bytes + 255) & ~(size_t)255;
        return r;
    };
    unsigned short* w2frag = (unsigned short*)alloc((size_t)4 * W2U * sizeof(unsigned short));
    uint4* bucket = (uint4*)alloc((size_t)NN * CAP * sizeof(uint4));
    int* cnt      = (int*)alloc((size_t)NN * sizeof(int));
    unsigned* xA  = (unsigned*)alloc((size_t)NN * 16 * sizeof(unsigned));
    unsigned* xB  = (unsigned*)alloc((size_t)NN * 16 * sizeof(unsigned));
    float* ans    = (float*)alloc((size_t)NN * 32 * sizeof(float));
    float* outf   = (float*)d_out;

    hipMemsetAsync(cnt, 0, (size_t)NN * sizeof(int), stream);

    buildfill_kernel<<<1363, 256, 0, stream>>>(ei, ej, attr, cnt, bucket,
                                               wp, feat, xA, w2frag);

    fused_kernel<<<NN / 16, 1024, 0, stream>>>(xA, (unsigned short*)xB, bucket, cnt,
                                               w2frag + 0 * (size_t)W2U, fcB[0], ans, outf, 0);
    fused_kernel<<<NN / 16, 1024, 0, stream>>>(xB, (unsigned short*)xA, bucket, cnt,
                                               w2frag + 1 * (size_t)W2U, fcB[1], ans, outf, 1);
    fused_kernel<<<NN / 16, 1024, 0, stream>>>(xA, (unsigned short*)xB, bucket, cnt,
                                               w2frag + 2 * (size_t)W2U, fcB[2], ans, outf, 1);
    fused_kernel<<<NN / 16, 1024, 0, stream>>>(xB, (unsigned short*)xA, bucket, cnt,
                                               w2frag + 3 * (size_t)W2U, fcB[3], ans, outf, 2);
}

// Round 19
// 94.955 us; speedup vs baseline: 2.6077x; 2.3418x over previous
//
#include <hip/hip_runtime.h>
#include <hip/hip_bf16.h>

#define NN 20000
#define NE 320000
#define NCH 17        // 16 conv slots + 1 fc slot, K chunks of 32
#define SROWU 552     // per-node LDS row stride (ushorts): 544 + 8 pad
#define CAP 64        // per-node edge bucket capacity (mean deg 16)
#define W2U (2 * NCH * 512)   // per-layer W2frag ushorts = 17408

typedef __attribute__((ext_vector_type(8))) short short8;
typedef __attribute__((ext_vector_type(4))) float f32x4;

__device__ __forceinline__ unsigned short f2bf(float v) {
    unsigned u = __float_as_uint(v);
    unsigned r = (u + 0x7fffu + ((u >> 16) & 1u)) >> 16;
    return (unsigned short)r;
}
__device__ __forceinline__ float bf2f(unsigned short s) {
    return __uint_as_float(((unsigned)s) << 16);
}

struct WPtrs { const float* cw[4]; const float* fw[4]; };

// x layout: per node 16 dwords; dword f = bf16(x[f]) | bf16(x[f+16])<<16

// ---- one build dispatch:
// [0,1250): edge->bucket fill (+basis weights);  [1250,1329): feat cast;
// [1329,1363): W2frag (pre-swizzled MFMA B-fragments, all 4 layers)
__global__ __launch_bounds__(256) void buildfill_kernel(const int* __restrict__ ei,
                                                        const int* __restrict__ ej,
                                                        const float* __restrict__ attr,
                                                        int* __restrict__ cnt,
                                                        uint4* __restrict__ bucket,
                                                        WPtrs wp,
                                                        const float* __restrict__ feat,
                                                        unsigned* __restrict__ x0,
                                                        unsigned short* __restrict__ w2frag) {
    int b = blockIdx.x, t = threadIdx.x;
    if (b < 1250) {
        int e = b * 256 + t;                     // 1250*256 == NE exactly
        int i = ei[e], j = ej[e];
        float2 a = ((const float2*)attr)[e];
        float d0 = fminf(fmaxf(a.x, -1.f), 1.f);
        float d1 = fminf(fmaxf(a.y, -1.f), 1.f);
        float tx = (d0 + 1.f) * 1.5f;
        float ty = (d1 + 1.f) * 1.5f;
        int ix = min(2, max(0, (int)floorf(tx)));
        int iy = min(2, max(0, (int)floorf(ty)));
        float ux = tx - (float)ix;
        float uy = ty - (float)iy;
        float m = (i != j) ? 1.f : 0.f;   // centerIgnore
        uint4 mm;
        mm.x = (unsigned)j | ((unsigned)(ix * 4 + iy) << 16);
        mm.y = (unsigned)f2bf((1.f - ux) * (1.f - uy) * m)
             | ((unsigned)f2bf((1.f - ux) * uy * m) << 16);
        mm.z = (unsigned)f2bf(ux * (1.f - uy) * m)
             | ((unsigned)f2bf(ux * uy * m) << 16);
        mm.w = 0;
        int slot = atomicAdd(&cnt[i], 1);
        if (slot < CAP) bucket[(size_t)i * CAP + slot] = mm;
    } else if (b < 1329) {
        int n = (b - 1250) * 256 + t;            // 79*256 = 20224 >= 20000
        if (n < NN) {
            const float4* fr = (const float4*)(feat + (size_t)n * 32);
            float4 v0 = fr[0], v1 = fr[1], v2 = fr[2], v3 = fr[3];
            float4 v4 = fr[4], v5 = fr[5], v6 = fr[6], v7 = fr[7];
            float lo[16] = {v0.x, v0.y, v0.z, v0.w, v1.x, v1.y, v1.z, v1.w,
                            v2.x, v2.y, v2.z, v2.w, v3.x, v3.y, v3.z, v3.w};
            float hi[16] = {v4.x, v4.y, v4.z, v4.w, v5.x, v5.y, v5.z, v5.w,
                            v6.x, v6.y, v6.z, v6.w, v7.x, v7.y, v7.z, v7.w};
            unsigned o[16];
#pragma unroll
            for (int f = 0; f < 16; f++)
                o[f] = (unsigned)f2bf(lo[f]) | ((unsigned)f2bf(hi[f]) << 16);
            uint4* dst = (uint4*)(x0 + (size_t)n * 16);
#pragma unroll
            for (int q = 0; q < 4; q++) {
                uint4 w; w.x = o[q*4]; w.y = o[q*4+1]; w.z = o[q*4+2]; w.w = o[q*4+3];
                dst[q] = w;
            }
        }
    } else {
        int id2 = (b - 1329) * 256 + t;          // 4l * 2tile * 17c * 64lane = 8704
        if (id2 < 8704) {
            int lane = id2 & 63;
            int c = (id2 >> 6) % NCH;
            int lt = id2 / (NCH * 64);
            int l = lt >> 1, tt = lt & 1;
            int kb = (lane >> 4) * 8;
            int col = tt * 16 + (lane & 15);
            short8 o;
#pragma unroll
            for (int i = 0; i < 8; i++) {
                int k = c * 32 + kb + i;
                float v = (k < 512) ? wp.cw[l][(size_t)k * 32 + col]
                                    : wp.fw[l][(size_t)(k - 512) * 32 + col];
                o[i] = (short)f2bf(v);
            }
            *(short8*)(w2frag + (size_t)id2 * 8) = o;
        }
    }
}

// ---- fused layer: 16 nodes/block, 1 wave/node.
// Phase A (scatter-by-MFMA): S_i = Phi_i^T . X_i, one mfma_16x16x32 per
// B-fragment per 32-edge chunk; D packed to bf16 in LDS.
// Phase B: waves 0,1: ans = S . W2 -- per chunk ONE ds_read_b128 for A,
// one for W, one MFMA. +bias/residual/relu.
// NOTE: the weight select MUST stay an equality cascade -- bit-tested
// ternaries ((d&4)?mm[i].z:mm[i].y) get strength-reduced to a variable-
// indexed array access -> mm[] demoted to scratch (rule #20), 2.3x slower.
__global__ __launch_bounds__(1024, 8) void fused_kernel(const unsigned* __restrict__ xin,
                                                        unsigned short* __restrict__ xout,
                                                        const uint4* __restrict__ bucket,
                                                        const int* __restrict__ cnt,
                                                        const unsigned short* __restrict__ w2frag,
                                                        const float* __restrict__ bias,
                                                        float* __restrict__ ansbuf,
                                                        float* __restrict__ outf,
                                                        int mode) {
    __shared__ unsigned short su[16][SROWU];
    int tid = threadIdx.x;
    int wv = tid >> 6, lane = tid & 63;
    int fcol = lane & 15;              // A-row (slot) / B-col (feature) role
    int kg = lane >> 4;                // edge octet within chunk
    int node = blockIdx.x * 16 + wv;
    int deg = min(cnt[node], CAP);
    const uint4* em = bucket + (size_t)node * CAP;

    f32x4 acc0 = {0.f, 0.f, 0.f, 0.f};
    f32x4 acc1 = {0.f, 0.f, 0.f, 0.f};

    for (int qb = 0; qb < deg; qb += 32) {
        int last = deg - 1;
        int qa = qb + kg * 8;
        uint4 mm[8];
#pragma unroll
        for (int i = 0; i < 8; i++) mm[i] = em[min(qa + i, last)];
        unsigned xv[8];
#pragma unroll
        for (int i = 0; i < 8; i++)
            xv[i] = xin[(size_t)(mm[i].x & 0xFFFF) * 16 + fcol];
        short8 av, bv0, bv1;
#pragma unroll
        for (int i = 0; i < 8; i++) {
            bv0[i] = (short)(unsigned short)(xv[i] & 0xFFFF);
            bv1[i] = (short)(unsigned short)(xv[i] >> 16);
            int d = fcol - (int)(mm[i].x >> 16);
            unsigned bits = (d == 0) ? (mm[i].y & 0xFFFFu)
                          : (d == 1) ? (mm[i].y >> 16)
                          : (d == 4) ? (mm[i].z & 0xFFFFu)
                          : (d == 5) ? (mm[i].z >> 16) : 0u;
            if (qa + i >= deg) bits = 0u;
            av[i] = (short)bits;
        }
        acc0 = __builtin_amdgcn_mfma_f32_16x16x32_bf16(av, bv0, acc0, 0, 0, 0);
        acc1 = __builtin_amdgcn_mfma_f32_16x16x32_bf16(av, bv1, acc1, 0, 0, 0);
    }
    // D -> LDS as bf16: lane holds D[slot = kg*4+r][fin = fcol and fcol+16]
#pragma unroll
    for (int r = 0; r < 4; r++) {
        int sr = kg * 4 + r;
        su[wv][sr * 32 + fcol]      = f2bf(acc0[r]);
        su[wv][sr * 32 + 16 + fcol] = f2bf(acc1[r]);
    }
    if (lane < 32) {   // fc slot: own features (bf16 bits direct from x)
        unsigned xv = xin[(size_t)node * 16 + (lane & 15)];
        su[wv][512 + lane] = (unsigned short)((lane < 16) ? (xv & 0xFFFF) : (xv >> 16));
    }
    __syncthreads();

    if (wv < 2) {
        int row = lane & 15;            // A-row = node within block
        int kb = (lane >> 4) * 8;
        const unsigned short* bp = w2frag + (size_t)wv * NCH * 512 + lane * 8;
        f32x4 acc = {0.f, 0.f, 0.f, 0.f};
#pragma unroll
        for (int c = 0; c < NCH; c++) {
            short8 av = *(const short8*)&su[row][c * 32 + kb];
            short8 bv = *(const short8*)(bp + (size_t)c * 512);
            acc = __builtin_amdgcn_mfma_f32_16x16x32_bf16(av, bv, acc, 0, 0, 0);
        }
        // D: col=lane&15 (feature), row=(lane>>4)*4+r (node within block)
        int fo = wv * 16 + (lane & 15);
        float bs = bias[fo];
        // interleaved xout position (ushort index within node): (fo&15)*2 + (fo>>4)
        int xpos = (fo & 15) * 2 + (fo >> 4);
#pragma unroll
        for (int r = 0; r < 4; r++) {
            int nd = blockIdx.x * 16 + (lane >> 4) * 4 + r;
            float val = acc[r] + bs;
            if (mode) val += ansbuf[(size_t)nd * 32 + fo];
            if (mode == 2) {
                outf[(size_t)nd * 32 + fo] = val * (1.f / 128.f);
            } else {
                ansbuf[(size_t)nd * 32 + fo] = val;
                xout[(size_t)nd * 32 + xpos] = f2bf(fmaxf(val, 0.f));
            }
        }
    }
}

extern "C" void kernel_launch(void* const* d_in, const int* in_sizes, int n_in,
                              void* d_out, int out_size, void* d_ws, size_t ws_size,
                              hipStream_t stream) {
    const float* feat = (const float*)d_in[0];
    const int* ei = (const int*)d_in[1];
    const int* ej = (const int*)d_in[2];
    const float* attr = (const float*)d_in[3];
    WPtrs wp;
    const float* fcB[4];
    if (n_in >= 16) {
        for (int l = 0; l < 4; l++) {
            wp.cw[l] = (const float*)d_in[4 + l];
            wp.fw[l] = (const float*)d_in[8 + l];
            fcB[l]   = (const float*)d_in[12 + l];
        }
    } else {
        const float* cb = (const float*)d_in[4];
        const float* fb = (const float*)d_in[5];
        const float* bb = (const float*)d_in[6];
        for (int l = 0; l < 4; l++) {
            wp.cw[l] = cb + (size_t)l * 16 * 32 * 32;
            wp.fw[l] = fb + (size_t)l * 32 * 32;
            fcB[l]   = bb + (size_t)l * 32;
        }
    }

    char* p = (char*)d_ws;
    auto alloc = [&](size_t bytes) -> void* {
        void* r = (void*)p;
        p += (bytes + 255) & ~(size_t)255;
        return r;
    };
    unsigned short* w2frag = (unsigned short*)alloc((size_t)4 * W2U * sizeof(unsigned short));
    uint4* bucket = (uint4*)alloc((size_t)NN * CAP * sizeof(uint4));
    int* cnt      = (int*)alloc((size_t)NN * sizeof(int));
    unsigned* xA  = (unsigned*)alloc((size_t)NN * 16 * sizeof(unsigned));
    unsigned* xB  = (unsigned*)alloc((size_t)NN * 16 * sizeof(unsigned));
    float* ans    = (float*)alloc((size_t)NN * 32 * sizeof(float));
    float* outf   = (float*)d_out;

    hipMemsetAsync(cnt, 0, (size_t)NN * sizeof(int), stream);

    buildfill_kernel<<<1363, 256, 0, stream>>>(ei, ej, attr, cnt, bucket,
                                               wp, feat, xA, w2frag);

    fused_kernel<<<NN / 16, 1024, 0, stream>>>(xA, (unsigned short*)xB, bucket, cnt,
                                               w2frag + 0 * (size_t)W2U, fcB[0], ans, outf, 0);
    fused_kernel<<<NN / 16, 1024, 0, stream>>>(xB, (unsigned short*)xA, bucket, cnt,
                                               w2frag + 1 * (size_t)W2U, fcB[1], ans, outf, 1);
    fused_kernel<<<NN / 16, 1024, 0, stream>>>(xA, (unsigned short*)xB, bucket, cnt,
                                               w2frag + 2 * (size_t)W2U, fcB[2], ans, outf, 1);
    fused_kernel<<<NN / 16, 1024, 0, stream>>>(xB, (unsigned short*)xA, bucket, cnt,
                                               w2frag + 3 * (size_t)W2U, fcB[3], ans, outf, 2);
}